// Round 12
// baseline (66.219 us; speedup 1.0000x reference)
//
#include <hip/hip_runtime.h>
#include <stdint.h>

// Problem constants: x (4, 8192, 512) f32, A/B (512, 64), h0 scalar.
#define NBATCH 4
#define LSEQ   8192
#define CH     512
#define ORDER  64
#define KTAP   256           // validated R3-R11: tail < 1e-5, threshold 5.86e-3
#define NW     9             // windows T0_w = 32w+15 cover t in [0,256) once/row

typedef _Float16 half8 __attribute__((ext_vector_type(8)));
typedef __fp16   fp16x2 __attribute__((ext_vector_type(2)));
typedef float    f32x4 __attribute__((ext_vector_type(4)));

#define AFRAG_HALFS  ((size_t)CH * NW * 64 * 8)        // 4.7 MB
#define WS_NEED      (AFRAG_HALFS * 2)

// ---- fir geometry ----------------------------------------------------------
// Block = 16 ch x 512 n (2 tiles of 256) x 1 batch; 256 threads; grid 2048.
// xs[16 ch][792 halves] f16 pair-packed, idx 0 <-> row n0-271 (idx of B-frag
// base = 16j+8g-32w+256+256ti, always %8==0 -> aligned b128 reads).
// Row stride 1584 B == 16 mod 128 -> stage b32 writes 2-way (free), b128
// fragment reads conflict-free. lds_out[16][260 f32] ALIASED onto xs (all
// MFMAs complete before epilogue; R9 validated the alias).
#define XROWB 1584
#define SMEMB (16 * XROWB)   // 25344 B -> up to 6 blocks/CU by LDS
#define LOWB  1040
#define PAIRS 392            // row-pairs staged: rows n0-271 .. n0+512

__device__ __forceinline__ uint32_t pkrtz(float lo, float hi) {
    fp16x2 v = __builtin_amdgcn_cvt_pkrtz(lo, hi);
    return __builtin_bit_cast(uint32_t, v);
}

// ---------------------------------------------------------------------------
// Kernel 1: IIR impulse response -> per-channel MFMA A-fragments (proven
// R7-R11). A_w[i][k] = Kx[32w+15+i-k], lane l: i=l&15, k=8*(l>>4)+e; h0
// folded into Kx[0]; Kx zero outside [0,KTAP). 4 channels/block.
// ---------------------------------------------------------------------------
__global__ __launch_bounds__(256) void rtf_afrag(const float* __restrict__ A,
                                                 const float* __restrict__ B,
                                                 const float* __restrict__ h0,
                                                 _Float16* __restrict__ afr) {
    __shared__ float Ksh[4][KTAP];
    const int wv = threadIdx.x >> 6, lane = threadIdx.x & 63;
    const int c  = blockIdx.x * 4 + wv;
    const float a  = A[c * ORDER + lane];
    const float bc = B[c * ORDER + lane];
    const float h0v = h0[0];
    float s = 0.0f;
    for (int t = 0; t < KTAP; ++t) {
        const float s1 = __shfl(s, 0);
        const float bt = (t < ORDER) ? __shfl(bc, t) : 0.0f;
        const float y  = bt + s1;
        float su = __shfl_down(s, 1);
        if (lane == ORDER - 1) su = 0.0f;
        s = su - a * y;
        if (lane == 0) Ksh[wv][t] = (t == 0) ? (y + h0v) : y;
    }
    __syncthreads();
    const int i = lane & 15, g = lane >> 4;
    for (int w = 0; w < NW; ++w) {
        half8 hv;
#pragma unroll
        for (int e = 0; e < 8; ++e) {
            const int t = 32 * w + 15 + i - 8 * g - e;
            hv[e] = (_Float16)((t >= 0 && t < KTAP) ? Ksh[wv][t] : 0.0f);
        }
        *reinterpret_cast<half8*>(afr + ((size_t)(c * NW + w) * 64 + lane) * 8) = hv;
    }
}

// ---------------------------------------------------------------------------
// Kernel 2: banded-Toeplitz MFMA FIR + gelu, direct f32 staging, small blocks
// for multi-block-per-CU overlap (R8 post-mortem: its 38.8us was the SERIAL
// sum of pipe costs; concurrency is the lever).
// Grid 2048 = 16 n-tiles x 4 batches x 32 chgrps, chgrp-major per XCD.
// Stage: 392 row-pairs x 16 ch; all float4 loads issued, then packed b32 LDS
// writes. Main: w-outer, A-frag global (L2-resident), B-frag ds_read_b128
// 1:1 MFMA, acc[2][4]. Epilogue per tile: gelu -> lds_out (aliased) ->
// 64B-coalesced float4 stores.
// ---------------------------------------------------------------------------
__global__ __launch_bounds__(256) void fir_direct(const float* __restrict__ x,
                                                  const _Float16* __restrict__ afr,
                                                  float* __restrict__ out) {
    __shared__ __align__(16) char smem[SMEMB];
    const int gid     = blockIdx.x;
    const int logical = (gid & 7) * 256 + (gid >> 3);   // bijective (2048%8==0)
    const int chgrp   = logical >> 6;                   // 0..31, 4 per XCD
    const int bb      = (logical >> 4) & 3;
    const int tg      = logical & 15;
    const int n0      = tg * 512;
    const int c0      = chgrp * 16;

    // ---- stage: loads first (14 float4 in flight), then packed LDS writes ----
    {
        const int q  = threadIdx.x & 3;      // channel quad
        const int pr = threadIdx.x >> 2;     // 0..63 pair slot
        const float* xsrc = x + (size_t)bb * LSEQ * CH + c0 + q * 4;
        f32x4 L0[7], L1[7];
#pragma unroll
        for (int i = 0; i < 7; ++i) {
            const int p = pr + 64 * i;
            f32x4 z = {0.f, 0.f, 0.f, 0.f};
            L0[i] = z; L1[i] = z;
            if (p < PAIRS) {
                const int r0 = n0 - 271 + 2 * p;
                if ((unsigned)r0 < LSEQ)       L0[i] = *reinterpret_cast<const f32x4*>(xsrc + (size_t)r0 * CH);
                if ((unsigned)(r0 + 1) < LSEQ) L1[i] = *reinterpret_cast<const f32x4*>(xsrc + (size_t)(r0 + 1) * CH);
            }
        }
#pragma unroll
        for (int i = 0; i < 7; ++i) {
            const int p = pr + 64 * i;
            if (p < PAIRS) {
                char* wb = smem + (size_t)(4 * q) * XROWB + 4 * p;
                *reinterpret_cast<uint32_t*>(wb + 0 * XROWB) = pkrtz(L0[i][0], L1[i][0]);
                *reinterpret_cast<uint32_t*>(wb + 1 * XROWB) = pkrtz(L0[i][1], L1[i][1]);
                *reinterpret_cast<uint32_t*>(wb + 2 * XROWB) = pkrtz(L0[i][2], L1[i][2]);
                *reinterpret_cast<uint32_t*>(wb + 3 * XROWB) = pkrtz(L0[i][3], L1[i][3]);
            }
        }
    }
    __syncthreads();

    // ---- main: 9 windows x 2 tiles x 4 ch/wave ----
    const int wid = threadIdx.x >> 6, lane = threadIdx.x & 63;
    const int j = lane & 15, g = lane >> 4;
    const int c0w = c0 + wid * 4;
    const _Float16* af = afr + (size_t)lane * 8;

    f32x4 acc[2][4];
#pragma unroll
    for (int ti = 0; ti < 2; ++ti)
#pragma unroll
        for (int q = 0; q < 4; ++q) acc[ti][q] = (f32x4){0.f, 0.f, 0.f, 0.f};

#pragma unroll
    for (int w = 0; w < NW; ++w) {
        half8 a[4];
#pragma unroll
        for (int q = 0; q < 4; ++q)
            a[q] = *reinterpret_cast<const half8*>(af + (size_t)((c0w + q) * NW + w) * 512);
        const int idx0 = 16 * j + 8 * g - 32 * w + 256;   // %8==0, b128-aligned
#pragma unroll
        for (int ti = 0; ti < 2; ++ti) {
#pragma unroll
            for (int q = 0; q < 4; ++q) {
                const half8 bv = *reinterpret_cast<const half8*>(
                    smem + (size_t)(wid * 4 + q) * XROWB + 2 * (idx0 + 256 * ti));
                acc[ti][q] = __builtin_amdgcn_mfma_f32_16x16x32_f16(a[q], bv, acc[ti][q], 0, 0, 0);
            }
        }
    }

    // ---- epilogue: per tile, gelu -> lds_out (aliases xs) -> float4 stores ----
    const int cq  = threadIdx.x & 3;
    const int nr0 = threadIdx.x >> 2;        // 0..63
#pragma unroll
    for (int ti = 0; ti < 2; ++ti) {
        __syncthreads();                     // xs reads / prev-tile store reads done
#pragma unroll
        for (int q = 0; q < 4; ++q) {
            f32x4 o;
#pragma unroll
            for (int r = 0; r < 4; ++r) {
                const float y  = acc[ti][q][r];
                const float wv = fmaf(y * y, 0.14270963f, 1.5957691f);
                const float e  = __expf(y * wv);
                o[r] = y - y * __builtin_amdgcn_rcpf(e + 1.0f);
            }
            *reinterpret_cast<f32x4*>(smem + (size_t)(wid * 4 + q) * LOWB
                                      + 4 * (16 * j + 4 * g)) = o;
        }
        __syncthreads();
        float* obp = out + ((size_t)bb * LSEQ + n0 + ti * 256) * CH + c0 + 4 * cq;
#pragma unroll
        for (int it = 0; it < 4; ++it) {
            const int n = nr0 + 64 * it;
            f32x4 o;
            o[0] = *reinterpret_cast<const float*>(smem + (size_t)(4 * cq + 0) * LOWB + 4 * n);
            o[1] = *reinterpret_cast<const float*>(smem + (size_t)(4 * cq + 1) * LOWB + 4 * n);
            o[2] = *reinterpret_cast<const float*>(smem + (size_t)(4 * cq + 2) * LOWB + 4 * n);
            o[3] = *reinterpret_cast<const float*>(smem + (size_t)(4 * cq + 3) * LOWB + 4 * n);
            *reinterpret_cast<f32x4*>(obp + (size_t)n * CH) = o;
        }
    }
}

// ======================== FALLBACK (R5, proven 138us) =======================
#define RINGF 32
#define CPBF  256
__global__ __launch_bounds__(ORDER) void rtf_impulse_fb(const float* __restrict__ A,
                                                        const float* __restrict__ B,
                                                        const float* __restrict__ h0,
                                                        float* __restrict__ kt4) {
    const int c = blockIdx.x, lane = threadIdx.x;
    const float a = A[c * ORDER + lane], bc = B[c * ORDER + lane], h0v = h0[0];
    float s = 0.0f;
    for (int t = 0; t < KTAP; ++t) {
        const float s1 = __shfl(s, 0);
        const float bt = (t < ORDER) ? __shfl(bc, t) : 0.0f;
        const float y  = bt + s1;
        float su = __shfl_down(s, 1);
        if (lane == ORDER - 1) su = 0.0f;
        s = su - a * y;
        if (lane == 0) kt4[((size_t)(t >> 2) * CH + c) * 4 + (t & 3)] = (t == 0) ? (y + h0v) : y;
    }
}
__global__ __launch_bounds__(CPBF) void fir_gelu_fb(const float* __restrict__ x,
                                                    const float* __restrict__ kt4,
                                                    float* __restrict__ out) {
    const int h = blockIdx.x;
    const int logical = ((h & 7) << 8) | (h >> 3);
    const int tile = logical & 255, sl = logical >> 8;
    const int cb = sl & 1, b = sl >> 1;
    const int c = cb * CPBF + threadIdx.x;
    const int n0 = tile * RINGF;
    const float* xb = x + (size_t)b * LSEQ * CH + c;
    const float4* kt4v = (const float4*)kt4;
    float acc[RINGF]; float ring[RINGF]; float px[2][8]; float kbuf[2][8];
#pragma unroll
    for (int r = 0; r < RINGF; ++r) acc[r] = 0.0f;
#pragma unroll
    for (int i = 0; i < RINGF; ++i) ring[i] = xb[(size_t)(n0 + i) * CH];
    {
        const float4 ka = kt4v[(size_t)0 * CH + c];
        const float4 kb = kt4v[(size_t)1 * CH + c];
        kbuf[0][0] = ka.x; kbuf[0][1] = ka.y; kbuf[0][2] = ka.z; kbuf[0][3] = ka.w;
        kbuf[0][4] = kb.x; kbuf[0][5] = kb.y; kbuf[0][6] = kb.z; kbuf[0][7] = kb.w;
#pragma unroll
        for (int g2 = 0; g2 < 8; ++g2) {
            const int m = n0 - 1 - g2;
            px[0][g2] = (m >= 0) ? xb[(size_t)m * CH] : 0.0f;
        }
    }
    for (int tb = 0; tb < KTAP; tb += RINGF) {
#pragma unroll
        for (int qq = 0; qq < 4; ++qq) {
            const int cur = qq & 1, nxt = cur ^ 1;
            const int tn = tb + 8 * (qq + 1);
            if (tn < KTAP) {
                const float4 ka = kt4v[(size_t)(tn >> 2) * CH + c];
                const float4 kb = kt4v[(size_t)((tn >> 2) + 1) * CH + c];
                kbuf[nxt][0] = ka.x; kbuf[nxt][1] = ka.y; kbuf[nxt][2] = ka.z; kbuf[nxt][3] = ka.w;
                kbuf[nxt][4] = kb.x; kbuf[nxt][5] = kb.y; kbuf[nxt][6] = kb.z; kbuf[nxt][7] = kb.w;
#pragma unroll
                for (int g2 = 0; g2 < 8; ++g2) {
                    const int m = n0 - tn - 1 - g2;
                    px[nxt][g2] = (m >= 0) ? xb[(size_t)m * CH] : 0.0f;
                }
            }
#pragma unroll
            for (int g2 = 0; g2 < 8; ++g2) {
                const int tq = 8 * qq + g2;
                const float kv = kbuf[cur][g2];
#pragma unroll
                for (int r = 0; r < RINGF; ++r)
                    acc[r] = fmaf(kv, ring[(r - tq) & (RINGF - 1)], acc[r]);
                ring[(RINGF - 1 - tq) & (RINGF - 1)] = px[cur][g2];
            }
        }
    }
    float* ob = out + ((size_t)b * LSEQ + n0) * CH + c;
#pragma unroll
    for (int r = 0; r < RINGF; ++r) {
        const float y = acc[r];
        const float wv = fmaf(y * y, 0.14270963f, 1.5957691f);
        const float e = __expf(y * wv);
        ob[(size_t)r * CH] = y - y * __builtin_amdgcn_rcpf(e + 1.0f);
    }
}

extern "C" void kernel_launch(void* const* d_in, const int* in_sizes, int n_in,
                              void* d_out, int out_size, void* d_ws, size_t ws_size,
                              hipStream_t stream) {
    const float* x  = (const float*)d_in[0];
    const float* A  = (const float*)d_in[1];
    const float* B  = (const float*)d_in[2];
    const float* h0 = (const float*)d_in[3];
    float* out = (float*)d_out;

    if (ws_size >= WS_NEED) {
        _Float16* afr = (_Float16*)d_ws;
        rtf_afrag<<<dim3(CH / 4), dim3(256), 0, stream>>>(A, B, h0, afr);
        fir_direct<<<dim3(2048), dim3(256), 0, stream>>>(x, afr, out);
    } else {
        float* kt4 = (float*)d_ws;  // 512 KB
        rtf_impulse_fb<<<dim3(CH), dim3(ORDER), 0, stream>>>(A, B, h0, kt4);
        fir_gelu_fb<<<dim3((LSEQ / RINGF) * (CH / CPBF) * NBATCH), dim3(CPBF), 0, stream>>>(x, kt4, out);
    }
}

// Round 13
// 65.367 us; speedup vs baseline: 1.0130x; 1.0130x over previous
//
#include <hip/hip_runtime.h>
#include <stdint.h>

// Problem constants: x (4, 8192, 512) f32, A/B (512, 64), h0 scalar.
#define NBATCH 4
#define LSEQ   8192
#define CH     512
#define ORDER  64
#define KTAP   256           // validated R3-R12: tail < 1e-5, threshold 5.86e-3
#define NW     9             // windows T0_w = 32w+15 cover t in [0,256) once/row

typedef _Float16 half8 __attribute__((ext_vector_type(8)));
typedef __fp16   fp16x2 __attribute__((ext_vector_type(2)));
typedef float    f32x4 __attribute__((ext_vector_type(4)));

#define AFRAG_HALFS  ((size_t)CH * NW * 64 * 8)        // 4.7 MB
#define WS_NEED      (AFRAG_HALFS * 2)

// ---- fir geometry (R12, proven correct) ------------------------------------
#define XROWB 1584
#define SMEMB (16 * XROWB)   // 25344 B -> 4 blocks/CU within LDS budget
#define LOWB  1040
#define PAIRS 392            // row-pairs staged: rows n0-271 .. n0+512

__device__ __forceinline__ uint32_t pkrtz(float lo, float hi) {
    fp16x2 v = __builtin_amdgcn_cvt_pkrtz(lo, hi);
    return __builtin_bit_cast(uint32_t, v);
}

// ---------------------------------------------------------------------------
// Kernel 1: IIR impulse response -> per-channel MFMA A-fragments (proven
// R7-R12). A_w[i][k] = Kx[32w+15+i-k], lane l: i=l&15, k=8*(l>>4)+e; h0
// folded into Kx[0]; Kx zero outside [0,KTAP). 4 channels/block.
// ---------------------------------------------------------------------------
__global__ __launch_bounds__(256) void rtf_afrag(const float* __restrict__ A,
                                                 const float* __restrict__ B,
                                                 const float* __restrict__ h0,
                                                 _Float16* __restrict__ afr) {
    __shared__ float Ksh[4][KTAP];
    const int wv = threadIdx.x >> 6, lane = threadIdx.x & 63;
    const int c  = blockIdx.x * 4 + wv;
    const float a  = A[c * ORDER + lane];
    const float bc = B[c * ORDER + lane];
    const float h0v = h0[0];
    float s = 0.0f;
    for (int t = 0; t < KTAP; ++t) {
        const float s1 = __shfl(s, 0);
        const float bt = (t < ORDER) ? __shfl(bc, t) : 0.0f;
        const float y  = bt + s1;
        float su = __shfl_down(s, 1);
        if (lane == ORDER - 1) su = 0.0f;
        s = su - a * y;
        if (lane == 0) Ksh[wv][t] = (t == 0) ? (y + h0v) : y;
    }
    __syncthreads();
    const int i = lane & 15, g = lane >> 4;
    for (int w = 0; w < NW; ++w) {
        half8 hv;
#pragma unroll
        for (int e = 0; e < 8; ++e) {
            const int t = 32 * w + 15 + i - 8 * g - e;
            hv[e] = (_Float16)((t >= 0 && t < KTAP) ? Ksh[wv][t] : 0.0f);
        }
        *reinterpret_cast<half8*>(afr + ((size_t)(c * NW + w) * 64 + lane) * 8) = hv;
    }
}

// ---------------------------------------------------------------------------
// Kernel 2: R12's fir_direct with the register budget UNLOCKED.
// __launch_bounds__(256, 4): 4 waves/EU -> 16 waves/CU (4 blocks/CU, matches
// the 25.3KB LDS limit) and a 128-VGPR budget so (a) all 14 stage loads stay
// in flight (R12's VGPR=60 serialized them into 7 HBM round-trips/wave) and
// (b) A-fragments double-buffer across windows (a_nxt loads hide L2 latency
// under the previous window's 8 MFMAs).
// ---------------------------------------------------------------------------
__global__ __launch_bounds__(256, 4) void fir_direct(const float* __restrict__ x,
                                                     const _Float16* __restrict__ afr,
                                                     float* __restrict__ out) {
    __shared__ __align__(16) char smem[SMEMB];
    const int gid     = blockIdx.x;
    const int logical = (gid & 7) * 256 + (gid >> 3);   // bijective (2048%8==0)
    const int chgrp   = logical >> 6;                   // 0..31, 4 per XCD
    const int bb      = (logical >> 4) & 3;
    const int tg      = logical & 15;
    const int n0      = tg * 512;
    const int c0      = chgrp * 16;

    // ---- stage: all 14 float4 loads in flight, then packed LDS writes ----
    {
        const int q  = threadIdx.x & 3;      // channel quad
        const int pr = threadIdx.x >> 2;     // 0..63 pair slot
        const float* xsrc = x + (size_t)bb * LSEQ * CH + c0 + q * 4;
        f32x4 L0[7], L1[7];
#pragma unroll
        for (int i = 0; i < 7; ++i) {
            const int p = pr + 64 * i;
            f32x4 z = {0.f, 0.f, 0.f, 0.f};
            L0[i] = z; L1[i] = z;
            if (p < PAIRS) {
                const int r0 = n0 - 271 + 2 * p;
                if ((unsigned)r0 < LSEQ)       L0[i] = *reinterpret_cast<const f32x4*>(xsrc + (size_t)r0 * CH);
                if ((unsigned)(r0 + 1) < LSEQ) L1[i] = *reinterpret_cast<const f32x4*>(xsrc + (size_t)(r0 + 1) * CH);
            }
        }
#pragma unroll
        for (int i = 0; i < 7; ++i) {
            const int p = pr + 64 * i;
            if (p < PAIRS) {
                char* wb = smem + (size_t)(4 * q) * XROWB + 4 * p;
                *reinterpret_cast<uint32_t*>(wb + 0 * XROWB) = pkrtz(L0[i][0], L1[i][0]);
                *reinterpret_cast<uint32_t*>(wb + 1 * XROWB) = pkrtz(L0[i][1], L1[i][1]);
                *reinterpret_cast<uint32_t*>(wb + 2 * XROWB) = pkrtz(L0[i][2], L1[i][2]);
                *reinterpret_cast<uint32_t*>(wb + 3 * XROWB) = pkrtz(L0[i][3], L1[i][3]);
            }
        }
    }
    __syncthreads();

    // ---- main: 9 windows x 2 tiles x 4 ch/wave, A-frags double-buffered ----
    const int wid = threadIdx.x >> 6, lane = threadIdx.x & 63;
    const int j = lane & 15, g = lane >> 4;
    const int c0w = c0 + wid * 4;
    const _Float16* af = afr + (size_t)lane * 8;

    f32x4 acc[2][4];
#pragma unroll
    for (int ti = 0; ti < 2; ++ti)
#pragma unroll
        for (int q = 0; q < 4; ++q) acc[ti][q] = (f32x4){0.f, 0.f, 0.f, 0.f};

    half8 a_cur[4], a_nxt[4];
#pragma unroll
    for (int q = 0; q < 4; ++q)
        a_cur[q] = *reinterpret_cast<const half8*>(af + (size_t)((c0w + q) * NW + 0) * 512);

#pragma unroll
    for (int w = 0; w < NW; ++w) {
        if (w < NW - 1) {
#pragma unroll
            for (int q = 0; q < 4; ++q)
                a_nxt[q] = *reinterpret_cast<const half8*>(af + (size_t)((c0w + q) * NW + (w + 1)) * 512);
        }
        const int idx0 = 16 * j + 8 * g - 32 * w + 256;   // %8==0, b128-aligned
#pragma unroll
        for (int ti = 0; ti < 2; ++ti) {
#pragma unroll
            for (int q = 0; q < 4; ++q) {
                const half8 bv = *reinterpret_cast<const half8*>(
                    smem + (size_t)(wid * 4 + q) * XROWB + 2 * (idx0 + 256 * ti));
                acc[ti][q] = __builtin_amdgcn_mfma_f32_16x16x32_f16(a_cur[q], bv, acc[ti][q], 0, 0, 0);
            }
        }
#pragma unroll
        for (int q = 0; q < 4; ++q) a_cur[q] = a_nxt[q];
    }

    // ---- epilogue: per tile, gelu -> lds_out (aliases xs) -> float4 stores ----
    const int cq  = threadIdx.x & 3;
    const int nr0 = threadIdx.x >> 2;        // 0..63
#pragma unroll
    for (int ti = 0; ti < 2; ++ti) {
        __syncthreads();                     // xs reads / prev-tile store reads done
#pragma unroll
        for (int q = 0; q < 4; ++q) {
            f32x4 o;
#pragma unroll
            for (int r = 0; r < 4; ++r) {
                const float y  = acc[ti][q][r];
                const float wv = fmaf(y * y, 0.14270963f, 1.5957691f);
                const float e  = __expf(y * wv);
                o[r] = y - y * __builtin_amdgcn_rcpf(e + 1.0f);
            }
            *reinterpret_cast<f32x4*>(smem + (size_t)(wid * 4 + q) * LOWB
                                      + 4 * (16 * j + 4 * g)) = o;
        }
        __syncthreads();
        float* obp = out + ((size_t)bb * LSEQ + n0 + ti * 256) * CH + c0 + 4 * cq;
#pragma unroll
        for (int it = 0; it < 4; ++it) {
            const int n = nr0 + 64 * it;
            f32x4 o;
            o[0] = *reinterpret_cast<const float*>(smem + (size_t)(4 * cq + 0) * LOWB + 4 * n);
            o[1] = *reinterpret_cast<const float*>(smem + (size_t)(4 * cq + 1) * LOWB + 4 * n);
            o[2] = *reinterpret_cast<const float*>(smem + (size_t)(4 * cq + 2) * LOWB + 4 * n);
            o[3] = *reinterpret_cast<const float*>(smem + (size_t)(4 * cq + 3) * LOWB + 4 * n);
            *reinterpret_cast<f32x4*>(obp + (size_t)n * CH) = o;
        }
    }
}

// ======================== FALLBACK (R5, proven 138us) =======================
#define RINGF 32
#define CPBF  256
__global__ __launch_bounds__(ORDER) void rtf_impulse_fb(const float* __restrict__ A,
                                                        const float* __restrict__ B,
                                                        const float* __restrict__ h0,
                                                        float* __restrict__ kt4) {
    const int c = blockIdx.x, lane = threadIdx.x;
    const float a = A[c * ORDER + lane], bc = B[c * ORDER + lane], h0v = h0[0];
    float s = 0.0f;
    for (int t = 0; t < KTAP; ++t) {
        const float s1 = __shfl(s, 0);
        const float bt = (t < ORDER) ? __shfl(bc, t) : 0.0f;
        const float y  = bt + s1;
        float su = __shfl_down(s, 1);
        if (lane == ORDER - 1) su = 0.0f;
        s = su - a * y;
        if (lane == 0) kt4[((size_t)(t >> 2) * CH + c) * 4 + (t & 3)] = (t == 0) ? (y + h0v) : y;
    }
}
__global__ __launch_bounds__(CPBF) void fir_gelu_fb(const float* __restrict__ x,
                                                    const float* __restrict__ kt4,
                                                    float* __restrict__ out) {
    const int h = blockIdx.x;
    const int logical = ((h & 7) << 8) | (h >> 3);
    const int tile = logical & 255, sl = logical >> 8;
    const int cb = sl & 1, b = sl >> 1;
    const int c = cb * CPBF + threadIdx.x;
    const int n0 = tile * RINGF;
    const float* xb = x + (size_t)b * LSEQ * CH + c;
    const float4* kt4v = (const float4*)kt4;
    float acc[RINGF]; float ring[RINGF]; float px[2][8]; float kbuf[2][8];
#pragma unroll
    for (int r = 0; r < RINGF; ++r) acc[r] = 0.0f;
#pragma unroll
    for (int i = 0; i < RINGF; ++i) ring[i] = xb[(size_t)(n0 + i) * CH];
    {
        const float4 ka = kt4v[(size_t)0 * CH + c];
        const float4 kb = kt4v[(size_t)1 * CH + c];
        kbuf[0][0] = ka.x; kbuf[0][1] = ka.y; kbuf[0][2] = ka.z; kbuf[0][3] = ka.w;
        kbuf[0][4] = kb.x; kbuf[0][5] = kb.y; kbuf[0][6] = kb.z; kbuf[0][7] = kb.w;
#pragma unroll
        for (int g2 = 0; g2 < 8; ++g2) {
            const int m = n0 - 1 - g2;
            px[0][g2] = (m >= 0) ? xb[(size_t)m * CH] : 0.0f;
        }
    }
    for (int tb = 0; tb < KTAP; tb += RINGF) {
#pragma unroll
        for (int qq = 0; qq < 4; ++qq) {
            const int cur = qq & 1, nxt = cur ^ 1;
            const int tn = tb + 8 * (qq + 1);
            if (tn < KTAP) {
                const float4 ka = kt4v[(size_t)(tn >> 2) * CH + c];
                const float4 kb = kt4v[(size_t)((tn >> 2) + 1) * CH + c];
                kbuf[nxt][0] = ka.x; kbuf[nxt][1] = ka.y; kbuf[nxt][2] = ka.z; kbuf[nxt][3] = ka.w;
                kbuf[nxt][4] = kb.x; kbuf[nxt][5] = kb.y; kbuf[nxt][6] = kb.z; kbuf[nxt][7] = kb.w;
#pragma unroll
                for (int g2 = 0; g2 < 8; ++g2) {
                    const int m = n0 - tn - 1 - g2;
                    px[nxt][g2] = (m >= 0) ? xb[(size_t)m * CH] : 0.0f;
                }
            }
#pragma unroll
            for (int g2 = 0; g2 < 8; ++g2) {
                const int tq = 8 * qq + g2;
                const float kv = kbuf[cur][g2];
#pragma unroll
                for (int r = 0; r < RINGF; ++r)
                    acc[r] = fmaf(kv, ring[(r - tq) & (RINGF - 1)], acc[r]);
                ring[(RINGF - 1 - tq) & (RINGF - 1)] = px[cur][g2];
            }
        }
    }
    float* ob = out + ((size_t)b * LSEQ + n0) * CH + c;
#pragma unroll
    for (int r = 0; r < RINGF; ++r) {
        const float y = acc[r];
        const float wv = fmaf(y * y, 0.14270963f, 1.5957691f);
        const float e = __expf(y * wv);
        ob[(size_t)r * CH] = y - y * __builtin_amdgcn_rcpf(e + 1.0f);
    }
}

extern "C" void kernel_launch(void* const* d_in, const int* in_sizes, int n_in,
                              void* d_out, int out_size, void* d_ws, size_t ws_size,
                              hipStream_t stream) {
    const float* x  = (const float*)d_in[0];
    const float* A  = (const float*)d_in[1];
    const float* B  = (const float*)d_in[2];
    const float* h0 = (const float*)d_in[3];
    float* out = (float*)d_out;

    if (ws_size >= WS_NEED) {
        _Float16* afr = (_Float16*)d_ws;
        rtf_afrag<<<dim3(CH / 4), dim3(256), 0, stream>>>(A, B, h0, afr);
        fir_direct<<<dim3(2048), dim3(256), 0, stream>>>(x, afr, out);
    } else {
        float* kt4 = (float*)d_ws;  // 512 KB
        rtf_impulse_fb<<<dim3(CH), dim3(ORDER), 0, stream>>>(A, B, h0, kt4);
        fir_gelu_fb<<<dim3((LSEQ / RINGF) * (CH / CPBF) * NBATCH), dim3(CPBF), 0, stream>>>(x, kt4, out);
    }
}